// Round 5
// baseline (407.991 us; speedup 1.0000x reference)
//
#include <hip/hip_runtime.h>

// 2-layer GCN (GraphConv, norm='both') for N=50000, E=1600000, 128->128->40.
// Graph build: chunked counting sort, no global atomics.
// h1/x2 stored bf16, tile-major [4 tiles][node][32 feats] so each tile (3.2MB)
// fits a per-XCD L2; agg1 blocks are XCD-swizzled (tile = (bid&7)>>1) so each
// XCD gathers only from its own L2-resident tile.

#define CHUNK 16384
#define CHUNK_SHIFT 14
#define NSLICES 64
#define TQ 16   // uints (bf16x2) per tile row = 32 features

typedef int iv4 __attribute__((ext_vector_type(4)));

__device__ __forceinline__ unsigned f2bf_bits(float f) {
    unsigned u = __float_as_uint(f);
    return (u + 0x7FFFu + ((u >> 16) & 1u)) >> 16;   // RNE
}
__device__ __forceinline__ unsigned pack_bf2(float a, float b) {
    return f2bf_bits(a) | (f2bf_bits(b) << 16);
}
__device__ __forceinline__ float bflo(unsigned v) { return __uint_as_float(v << 16); }
__device__ __forceinline__ float bfhi(unsigned v) { return __uint_as_float(v & 0xFFFF0000u); }

// ---------------- graph build ----------------

__global__ __launch_bounds__(256) void count_kernel(const int* __restrict__ src, const int* __restrict__ dst,
                                                    unsigned int* __restrict__ part, int E, int per) {
    __shared__ unsigned int h[CHUNK];
    int c = blockIdx.y, s = blockIdx.x, t = threadIdx.x;
    #pragma unroll
    for (int i = 0; i < CHUNK / 256; ++i) h[i * 256 + t] = 0;
    __syncthreads();
    int base = c << CHUNK_SHIFT;
    int beg = s * per;
    int end = min(E, beg + per);
    int nv = (end - beg) >> 2;
    const iv4* d4 = (const iv4*)(dst + beg);
    const iv4* s4 = (const iv4*)(src + beg);
    for (int i = t; i < nv; i += 256) {
        iv4 dv = __builtin_nontemporal_load(d4 + i);
        iv4 sv = __builtin_nontemporal_load(s4 + i);
        int x;
        x = dv.x - base; if ((unsigned)x < CHUNK) atomicAdd(&h[x], 1u);
        x = dv.y - base; if ((unsigned)x < CHUNK) atomicAdd(&h[x], 1u);
        x = dv.z - base; if ((unsigned)x < CHUNK) atomicAdd(&h[x], 1u);
        x = dv.w - base; if ((unsigned)x < CHUNK) atomicAdd(&h[x], 1u);
        x = sv.x - base; if ((unsigned)x < CHUNK) atomicAdd(&h[x], 0x10000u);
        x = sv.y - base; if ((unsigned)x < CHUNK) atomicAdd(&h[x], 0x10000u);
        x = sv.z - base; if ((unsigned)x < CHUNK) atomicAdd(&h[x], 0x10000u);
        x = sv.w - base; if ((unsigned)x < CHUNK) atomicAdd(&h[x], 0x10000u);
    }
    for (int e = beg + (nv << 2) + t; e < end; e += 256) {
        int x = dst[e] - base; if ((unsigned)x < CHUNK) atomicAdd(&h[x], 1u);
        x = src[e] - base;     if ((unsigned)x < CHUNK) atomicAdd(&h[x], 0x10000u);
    }
    __syncthreads();
    unsigned int* out = part + (((size_t)(c * NSLICES + s)) << CHUNK_SHIFT);
    #pragma unroll
    for (int i = 0; i < CHUNK / 256; ++i) __builtin_nontemporal_store(h[i * 256 + t], out + i * 256 + t);
}

__global__ __launch_bounds__(256) void reduce_kernel(const unsigned int* __restrict__ part,
                                                     float* __restrict__ norm_src, float* __restrict__ norm_dst,
                                                     int* __restrict__ deg_dst_i, int N) {
    int d = blockIdx.x * 256 + threadIdx.x;
    if (d >= N) return;
    int c = d >> CHUNK_SHIFT, idx = d & (CHUNK - 1);
    const unsigned int* p = part + (((size_t)c * NSLICES) << CHUNK_SHIFT) + idx;
    unsigned int dsum = 0, ssum = 0;
    #pragma unroll
    for (int s = 0; s < NSLICES; ++s) {
        unsigned int v = __builtin_nontemporal_load(p + ((size_t)s << CHUNK_SHIFT));
        dsum += v & 0xFFFFu;
        ssum += v >> 16;
    }
    deg_dst_i[d] = (int)dsum;
    norm_src[d] = rsqrtf(fmaxf((float)ssum, 1.0f));
    norm_dst[d] = rsqrtf(fmaxf((float)dsum, 1.0f));
}

__global__ __launch_bounds__(256) void scanA_kernel(const int* __restrict__ deg, int* __restrict__ bsum, int N) {
    __shared__ int wsum[4];
    int b = blockIdx.x, t = threadIdx.x, lane = t & 63, wid = t >> 6;
    int i0 = b * 1024 + t * 4;
    int s = 0;
    if (i0 + 3 < N) {
        int4 v = *(const int4*)(deg + i0);
        s = v.x + v.y + v.z + v.w;
    } else {
        for (int k = 0; k < 4; ++k) { int i = i0 + k; if (i < N) s += deg[i]; }
    }
    #pragma unroll
    for (int off = 32; off; off >>= 1) s += __shfl_down(s, off, 64);
    if (lane == 0) wsum[wid] = s;
    __syncthreads();
    if (t == 0) bsum[b] = wsum[0] + wsum[1] + wsum[2] + wsum[3];
}

__global__ __launch_bounds__(64) void scanB_kernel(int* __restrict__ bsum, int NB,
                                                   int* __restrict__ row_ptr, int N) {
    int t = threadIdx.x;
    int v = (t < NB) ? bsum[t] : 0;
    int x = v;
    #pragma unroll
    for (int off = 1; off < 64; off <<= 1) {
        int y = __shfl_up(x, off, 64);
        if (t >= off) x += y;
    }
    if (t < NB) bsum[t] = x - v;
    if (t == 63) row_ptr[N] = x;
}

__global__ __launch_bounds__(256) void scanC_kernel(const int* __restrict__ deg, const int* __restrict__ bsum,
                                                    int* __restrict__ row_ptr, int N) {
    __shared__ int wsum[4];
    int b = blockIdx.x, t = threadIdx.x, lane = t & 63, wid = t >> 6;
    int i0 = b * 1024 + t * 4;
    int4 v = make_int4(0, 0, 0, 0);
    if (i0 + 3 < N) v = *(const int4*)(deg + i0);
    else {
        v.x = (i0 < N) ? deg[i0] : 0;
        v.y = (i0 + 1 < N) ? deg[i0 + 1] : 0;
        v.z = (i0 + 2 < N) ? deg[i0 + 2] : 0;
        v.w = (i0 + 3 < N) ? deg[i0 + 3] : 0;
    }
    int tsum = v.x + v.y + v.z + v.w;
    int x = tsum;
    #pragma unroll
    for (int off = 1; off < 64; off <<= 1) {
        int y = __shfl_up(x, off, 64);
        if (lane >= off) x += y;
    }
    if (lane == 63) wsum[wid] = x;
    __syncthreads();
    int woff = 0;
    for (int k = 0; k < wid; ++k) woff += wsum[k];
    int base = bsum[b] + woff + (x - tsum);
    int e0 = base, e1 = e0 + v.x, e2 = e1 + v.y, e3 = e2 + v.z;
    if (i0 + 3 < N) *(int4*)(row_ptr + i0) = make_int4(e0, e1, e2, e3);
    else {
        if (i0 < N) row_ptr[i0] = e0;
        if (i0 + 1 < N) row_ptr[i0 + 1] = e1;
        if (i0 + 2 < N) row_ptr[i0 + 2] = e2;
        if (i0 + 3 < N) row_ptr[i0 + 3] = e3;
    }
}

__global__ __launch_bounds__(256) void offsets_kernel(unsigned int* __restrict__ part,
                                                      const int* __restrict__ row_ptr, int N) {
    int d = blockIdx.x * 256 + threadIdx.x;
    if (d >= N) return;
    int c = d >> CHUNK_SHIFT, idx = d & (CHUNK - 1);
    unsigned int* p = part + (((size_t)c * NSLICES) << CHUNK_SHIFT) + idx;
    unsigned int running = (unsigned int)row_ptr[d];
    #pragma unroll
    for (int s = 0; s < NSLICES; ++s) {
        unsigned int v = __builtin_nontemporal_load(p + ((size_t)s << CHUNK_SHIFT));
        __builtin_nontemporal_store(running, p + ((size_t)s << CHUNK_SHIFT));
        running += v & 0xFFFFu;
    }
}

__global__ __launch_bounds__(256) void scatter_kernel(const int* __restrict__ src, const int* __restrict__ dst,
                                                      const unsigned int* __restrict__ cum,
                                                      int* __restrict__ col, int E, int per) {
    __shared__ int cur[CHUNK];
    int c = blockIdx.y, s = blockIdx.x, t = threadIdx.x;
    const unsigned int* cc = cum + (((size_t)(c * NSLICES + s)) << CHUNK_SHIFT);
    #pragma unroll
    for (int i = 0; i < CHUNK / 256; ++i) cur[i * 256 + t] = (int)__builtin_nontemporal_load(cc + i * 256 + t);
    __syncthreads();
    int base = c << CHUNK_SHIFT;
    int beg = s * per;
    int end = min(E, beg + per);
    int nv = (end - beg) >> 2;
    const iv4* d4 = (const iv4*)(dst + beg);
    const iv4* s4 = (const iv4*)(src + beg);
    for (int i = t; i < nv; i += 256) {
        iv4 dv = __builtin_nontemporal_load(d4 + i);
        iv4 sv = __builtin_nontemporal_load(s4 + i);
        int x;
        x = dv.x - base; if ((unsigned)x < CHUNK) col[atomicAdd(&cur[x], 1)] = sv.x;
        x = dv.y - base; if ((unsigned)x < CHUNK) col[atomicAdd(&cur[x], 1)] = sv.y;
        x = dv.z - base; if ((unsigned)x < CHUNK) col[atomicAdd(&cur[x], 1)] = sv.z;
        x = dv.w - base; if ((unsigned)x < CHUNK) col[atomicAdd(&cur[x], 1)] = sv.w;
    }
    for (int e = beg + (nv << 2) + t; e < end; e += 256) {
        int x = dst[e] - base;
        if ((unsigned)x < CHUNK) col[atomicAdd(&cur[x], 1)] = src[e];
    }
}

// ---------------- dense layers ----------------

// h1t[tile][n][32f] = bf16( norm[n] * sum_k x[n][k] * W[k][tile*32+f] )
__global__ __launch_bounds__(256) void gemm1_kernel(const float* __restrict__ x, const float* __restrict__ norm,
                                                    const float* __restrict__ W, unsigned int* __restrict__ h1t,
                                                    int N, int NPAD) {
    __shared__ float xs[128 * 32];
    __shared__ float ws[128 * 64];
    int t = threadIdx.x;
    int rb = blockIdx.x * 32;
    int jb = blockIdx.y * 64;
    #pragma unroll
    for (int i = 0; i < 8; ++i) {
        int idx = i * 256 + t;
        int k = idx >> 4, j4 = (idx & 15) << 2;
        *(float4*)(ws + k * 64 + j4) = *(const float4*)(W + k * 128 + jb + j4);
    }
    #pragma unroll
    for (int i = 0; i < 4; ++i) {
        int idx = i * 256 + t;
        int row = idx >> 5, m = idx & 31, k4 = m << 2;
        int gr = rb + row;
        float4 v = make_float4(0.f, 0.f, 0.f, 0.f);
        if (gr < N) {
            v = *(const float4*)(x + (size_t)gr * 128 + k4);
            float nm = norm[gr];
            v.x *= nm; v.y *= nm; v.z *= nm; v.w *= nm;
        }
        int r = row ^ ((m & 7) << 2);
        xs[(k4 + 0) * 32 + r] = v.x;
        xs[(k4 + 1) * 32 + r] = v.y;
        xs[(k4 + 2) * 32 + r] = v.z;
        xs[(k4 + 3) * 32 + r] = v.w;
    }
    __syncthreads();
    int jg = t & 15, rg = t >> 4;
    int j = jg << 2, r0 = rg << 1;
    float a00 = 0, a01 = 0, a02 = 0, a03 = 0;
    float a10 = 0, a11 = 0, a12 = 0, a13 = 0;
    #pragma unroll 8
    for (int k = 0; k < 128; ++k) {
        int sw = ((k >> 2) & 7) << 2;
        float2 xv = *(const float2*)&xs[k * 32 + (r0 ^ sw)];
        float4 wv = *(const float4*)&ws[k * 64 + j];
        a00 += xv.x * wv.x; a01 += xv.x * wv.y; a02 += xv.x * wv.z; a03 += xv.x * wv.w;
        a10 += xv.y * wv.x; a11 += xv.y * wv.y; a12 += xv.y * wv.z; a13 += xv.y * wv.w;
    }
    int c0 = jb + j;
    int tile = c0 >> 5;
    int uo = (c0 & 31) >> 1;
    unsigned int* base = h1t + (size_t)tile * NPAD * TQ + uo;
    int gr0 = rb + r0;
    if (gr0 < N)     *(uint2*)(base + (size_t)gr0 * TQ)       = make_uint2(pack_bf2(a00, a01), pack_bf2(a02, a03));
    if (gr0 + 1 < N) *(uint2*)(base + (size_t)(gr0 + 1) * TQ) = make_uint2(pack_bf2(a10, a11), pack_bf2(a12, a13));
}

// XCD-partitioned gather: tile = (bid&7)>>1; each wave: 4 nodes x 16 lanes.
__global__ __launch_bounds__(256) void agg1_kernel(const int* __restrict__ row_ptr, const int* __restrict__ col,
                                                   const unsigned int* __restrict__ h1t, const float* __restrict__ norm_dst,
                                                   const float* __restrict__ b1, unsigned int* __restrict__ x2t,
                                                   int N, int NPAD, int Bt) {
    int bid = blockIdx.x;
    int xcd = bid & 7;
    int tile = xcd >> 1;
    int nblk = (bid >> 3) * 2 + (xcd & 1);
    if (nblk >= Bt) return;
    int t = threadIdx.x;
    int wid = t >> 6, lane = t & 63;
    int g = lane >> 4, f = lane & 15;
    int nb = nblk * 16 + wid * 4 + g;
    int beg = 0, deg = 0;
    if (nb < N) { beg = row_ptr[nb]; deg = row_ptr[nb + 1] - beg; }
    int md = deg;
    md = max(md, __shfl_xor(md, 16, 64));
    md = max(md, __shfl_xor(md, 32, 64));
    const unsigned int* hb = h1t + (size_t)tile * NPAD * TQ + f;
    const int* cp = col + beg;
    float ax = 0.f, ay = 0.f;
    for (int e = 0; e < md; e += 4) {
        int r = deg - e;
        if (r > 0) {
            int s0 = __builtin_nontemporal_load(cp + e);
            unsigned v = hb[(size_t)s0 * TQ];
            ax += bflo(v); ay += bfhi(v);
        }
        if (r > 1) {
            int s1 = __builtin_nontemporal_load(cp + e + 1);
            unsigned v = hb[(size_t)s1 * TQ];
            ax += bflo(v); ay += bfhi(v);
        }
        if (r > 2) {
            int s2 = __builtin_nontemporal_load(cp + e + 2);
            unsigned v = hb[(size_t)s2 * TQ];
            ax += bflo(v); ay += bfhi(v);
        }
        if (r > 3) {
            int s3 = __builtin_nontemporal_load(cp + e + 3);
            unsigned v = hb[(size_t)s3 * TQ];
            ax += bflo(v); ay += bfhi(v);
        }
    }
    if (nb < N) {
        float nd = norm_dst[nb];
        float2 b = ((const float2*)b1)[tile * TQ + f];
        float ox = fmaxf(ax * nd + b.x, 0.f);
        float oy = fmaxf(ay * nd + b.y, 0.f);
        __builtin_nontemporal_store(pack_bf2(ox, oy),
                                    x2t + (size_t)tile * NPAD * TQ + (size_t)nb * TQ + f);
    }
}

// h2[n][j] = bf16( norm[n] * sum_k x2[n][k] * W2[k][j] )   (W2 is 128x40)
__global__ __launch_bounds__(256) void gemm2_kernel(const unsigned int* __restrict__ x2t, const float* __restrict__ norm,
                                                    const float* __restrict__ W, unsigned short* __restrict__ h2u,
                                                    int N, int NPAD) {
    __shared__ float xs[128 * 64];
    __shared__ float ws2[128 * 40];
    int t = threadIdx.x;
    int rb = blockIdx.x * 64;
    #pragma unroll
    for (int i = 0; i < 5; ++i) {
        int idx = i * 256 + t;
        *(float4*)(ws2 + idx * 4) = *(const float4*)(W + idx * 4);
    }
    #pragma unroll
    for (int i = 0; i < 16; ++i) {
        int idx = i * 256 + t;               // 64 rows x 64 k-pairs
        int row = idx >> 6, kp = idx & 63;
        int gr = rb + row;
        unsigned v = 0; float nm = 0.f;
        if (gr < N) {
            v = x2t[(size_t)(kp >> 4) * NPAD * TQ + (size_t)gr * TQ + (kp & 15)];
            nm = norm[gr];
        }
        int r = row ^ (((kp >> 1) & 7) << 2);
        xs[(2 * kp + 0) * 64 + r] = bflo(v) * nm;
        xs[(2 * kp + 1) * 64 + r] = bfhi(v) * nm;
    }
    __syncthreads();
    int jg = t & 7, rg = t >> 3;
    int j = jg * 5, r0 = rg << 1;
    float acc0[5] = {0, 0, 0, 0, 0};
    float acc1[5] = {0, 0, 0, 0, 0};
    #pragma unroll 4
    for (int k = 0; k < 128; ++k) {
        int sw = ((k >> 2) & 7) << 2;
        float2 xv = *(const float2*)&xs[k * 64 + (r0 ^ sw)];
        #pragma unroll
        for (int c = 0; c < 5; ++c) {
            float w = ws2[k * 40 + j + c];
            acc0[c] += xv.x * w;
            acc1[c] += xv.y * w;
        }
    }
    int gr0 = rb + r0;
    if (gr0 < N) {
        #pragma unroll
        for (int c = 0; c < 5; ++c) h2u[(size_t)gr0 * 40 + j + c] = (unsigned short)f2bf_bits(acc0[c]);
    }
    if (gr0 + 1 < N) {
        #pragma unroll
        for (int c = 0; c < 5; ++c) h2u[(size_t)(gr0 + 1) * 40 + j + c] = (unsigned short)f2bf_bits(acc1[c]);
    }
}

// One wave per node (40 active lanes): out = sum h2[src] * norm_dst + b2
__global__ __launch_bounds__(256) void agg2_kernel(const int* __restrict__ row_ptr, const int* __restrict__ col,
                                                   const unsigned short* __restrict__ h2u, const float* __restrict__ norm_dst,
                                                   const float* __restrict__ b2, float* __restrict__ out, int N) {
    int n = (blockIdx.x * 256 + threadIdx.x) >> 6;
    int lane = threadIdx.x & 63;
    if (n >= N) return;
    int beg = row_ptr[n], end = row_ptr[n + 1];
    float acc = 0.f;
    bool act = lane < 40;
    int e = beg;
    for (; e + 4 <= end; e += 4) {
        int s0 = __builtin_nontemporal_load(col + e);
        int s1 = __builtin_nontemporal_load(col + e + 1);
        int s2 = __builtin_nontemporal_load(col + e + 2);
        int s3 = __builtin_nontemporal_load(col + e + 3);
        if (act) {
            acc += __uint_as_float((unsigned)h2u[(size_t)s0 * 40 + lane] << 16);
            acc += __uint_as_float((unsigned)h2u[(size_t)s1 * 40 + lane] << 16);
            acc += __uint_as_float((unsigned)h2u[(size_t)s2 * 40 + lane] << 16);
            acc += __uint_as_float((unsigned)h2u[(size_t)s3 * 40 + lane] << 16);
        }
    }
    for (; e < end; ++e) {
        int s = __builtin_nontemporal_load(col + e);
        if (act) acc += __uint_as_float((unsigned)h2u[(size_t)s * 40 + lane] << 16);
    }
    if (act) out[(size_t)n * 40 + lane] = acc * norm_dst[n] + b2[lane];
}

extern "C" void kernel_launch(void* const* d_in, const int* in_sizes, int n_in,
                              void* d_out, int out_size, void* d_ws, size_t ws_size,
                              hipStream_t stream) {
    const float* x  = (const float*)d_in[0];
    const int* src  = (const int*)d_in[1];
    const int* dst  = (const int*)d_in[2];
    const float* W1 = (const float*)d_in[3];
    const float* b1 = (const float*)d_in[4];
    const float* W2 = (const float*)d_in[5];
    const float* b2 = (const float*)d_in[6];
    float* out = (float*)d_out;

    int N = in_sizes[0] / 128;
    int E = in_sizes[1];
    int NPAD = (N + 63) & ~63;
    int NCHUNKS = (N + CHUNK - 1) >> CHUNK_SHIFT;
    int per = ((E + NSLICES - 1) / NSLICES + 3) & ~3;
    int NB = (N + 1023) / 1024;

    float* ws = (float*)d_ws;
    float* norm_src = ws;                                  // NPAD floats
    float* norm_dst = ws + NPAD;                           // NPAD floats
    int* deg_dst_i  = (int*)(ws + 2 * (size_t)NPAD);       // NPAD ints
    int* row_ptr    = (int*)(ws + 3 * (size_t)NPAD);       // N+1 ints
    int* bsum       = (int*)(ws + 4 * (size_t)NPAD);       // NB (<=64) ints
    int* col        = (int*)(ws + 4 * (size_t)NPAD + 64);  // E ints (+slack)
    size_t h1_off   = ((size_t)4 * NPAD + 64 + E + 15) & ~(size_t)15;
    unsigned int* h1t = (unsigned int*)(ws + h1_off);      // 4 tiles * NPAD*16 uints (12.8MB)
    unsigned int* x2t = h1t + (size_t)NPAD * 64;           // same size
    unsigned short* h2u = (unsigned short*)h1t;            // reuse (h1 dead after agg1)
    unsigned int* part = h1t;                              // 16.8MB, dead before gemm1

    dim3 cgrid(NSLICES, NCHUNKS);
    count_kernel<<<cgrid, 256, 0, stream>>>(src, dst, part, E, per);
    reduce_kernel<<<(N + 255) / 256, 256, 0, stream>>>(part, norm_src, norm_dst, deg_dst_i, N);
    scanA_kernel<<<NB, 256, 0, stream>>>(deg_dst_i, bsum, N);
    scanB_kernel<<<1, 64, 0, stream>>>(bsum, NB, row_ptr, N);
    scanC_kernel<<<NB, 256, 0, stream>>>(deg_dst_i, bsum, row_ptr, N);
    offsets_kernel<<<(N + 255) / 256, 256, 0, stream>>>(part, row_ptr, N);
    scatter_kernel<<<cgrid, 256, 0, stream>>>(src, dst, part, col, E, per);
    gemm1_kernel<<<dim3((N + 31) / 32, 2), 256, 0, stream>>>(x, norm_src, W1, h1t, N, NPAD);
    int Bt = (N + 15) / 16;
    int P = (Bt + 1) / 2;
    agg1_kernel<<<8 * P, 256, 0, stream>>>(row_ptr, col, h1t, norm_dst, b1, x2t, N, NPAD, Bt);
    gemm2_kernel<<<(N + 63) / 64, 256, 0, stream>>>(x2t, norm_src, W2, h2u, N, NPAD);
    agg2_kernel<<<(N * 64 + 255) / 256, 256, 0, stream>>>(row_ptr, col, h2u, norm_dst, b2, out, N);
}

// Round 7
// 253.095 us; speedup vs baseline: 1.6120x; 1.6120x over previous
//
#include <hip/hip_runtime.h>

// 2-layer GCN (GraphConv, norm='both') for N=50000, E=1600000, 128->128->40.
// Graph build: chunked counting sort, no global atomics.
// h1/x2 bf16 flat [n][128]; agg1: 4 nodes x 16 lanes/wave, uint4 (8-feature)
// gathers, branch-free per-group edge loops (exec-mask divergence only).

#define CHUNK 16384
#define CHUNK_SHIFT 14
#define NSLICES 64

typedef int iv4 __attribute__((ext_vector_type(4)));

__device__ __forceinline__ unsigned f2bf_bits(float f) {
    unsigned u = __float_as_uint(f);
    return (u + 0x7FFFu + ((u >> 16) & 1u)) >> 16;   // RNE
}
__device__ __forceinline__ unsigned pack_bf2(float a, float b) {
    return f2bf_bits(a) | (f2bf_bits(b) << 16);
}
__device__ __forceinline__ float bflo(unsigned v) { return __uint_as_float(v << 16); }
__device__ __forceinline__ float bfhi(unsigned v) { return __uint_as_float(v & 0xFFFF0000u); }

// ---------------- graph build ----------------

__global__ __launch_bounds__(256) void count_kernel(const int* __restrict__ src, const int* __restrict__ dst,
                                                    unsigned int* __restrict__ part, int E, int per) {
    __shared__ unsigned int h[CHUNK];
    int c = blockIdx.y, s = blockIdx.x, t = threadIdx.x;
    #pragma unroll
    for (int i = 0; i < CHUNK / 256; ++i) h[i * 256 + t] = 0;
    __syncthreads();
    int base = c << CHUNK_SHIFT;
    int beg = s * per;
    int end = min(E, beg + per);
    int nv = (end - beg) >> 2;
    const iv4* d4 = (const iv4*)(dst + beg);
    const iv4* s4 = (const iv4*)(src + beg);
    for (int i = t; i < nv; i += 256) {
        iv4 dv = __builtin_nontemporal_load(d4 + i);
        iv4 sv = __builtin_nontemporal_load(s4 + i);
        int x;
        x = dv.x - base; if ((unsigned)x < CHUNK) atomicAdd(&h[x], 1u);
        x = dv.y - base; if ((unsigned)x < CHUNK) atomicAdd(&h[x], 1u);
        x = dv.z - base; if ((unsigned)x < CHUNK) atomicAdd(&h[x], 1u);
        x = dv.w - base; if ((unsigned)x < CHUNK) atomicAdd(&h[x], 1u);
        x = sv.x - base; if ((unsigned)x < CHUNK) atomicAdd(&h[x], 0x10000u);
        x = sv.y - base; if ((unsigned)x < CHUNK) atomicAdd(&h[x], 0x10000u);
        x = sv.z - base; if ((unsigned)x < CHUNK) atomicAdd(&h[x], 0x10000u);
        x = sv.w - base; if ((unsigned)x < CHUNK) atomicAdd(&h[x], 0x10000u);
    }
    for (int e = beg + (nv << 2) + t; e < end; e += 256) {
        int x = dst[e] - base; if ((unsigned)x < CHUNK) atomicAdd(&h[x], 1u);
        x = src[e] - base;     if ((unsigned)x < CHUNK) atomicAdd(&h[x], 0x10000u);
    }
    __syncthreads();
    unsigned int* out = part + (((size_t)(c * NSLICES + s)) << CHUNK_SHIFT);
    #pragma unroll
    for (int i = 0; i < CHUNK / 256; ++i) __builtin_nontemporal_store(h[i * 256 + t], out + i * 256 + t);
}

__global__ __launch_bounds__(256) void reduce_kernel(const unsigned int* __restrict__ part,
                                                     float* __restrict__ norm_src, float* __restrict__ norm_dst,
                                                     int* __restrict__ deg_dst_i, int N) {
    int d = blockIdx.x * 256 + threadIdx.x;
    if (d >= N) return;
    int c = d >> CHUNK_SHIFT, idx = d & (CHUNK - 1);
    const unsigned int* p = part + (((size_t)c * NSLICES) << CHUNK_SHIFT) + idx;
    unsigned int dsum = 0, ssum = 0;
    #pragma unroll
    for (int s = 0; s < NSLICES; ++s) {
        unsigned int v = __builtin_nontemporal_load(p + ((size_t)s << CHUNK_SHIFT));
        dsum += v & 0xFFFFu;
        ssum += v >> 16;
    }
    deg_dst_i[d] = (int)dsum;
    norm_src[d] = rsqrtf(fmaxf((float)ssum, 1.0f));
    norm_dst[d] = rsqrtf(fmaxf((float)dsum, 1.0f));
}

__global__ __launch_bounds__(256) void scanA_kernel(const int* __restrict__ deg, int* __restrict__ bsum, int N) {
    __shared__ int wsum[4];
    int b = blockIdx.x, t = threadIdx.x, lane = t & 63, wid = t >> 6;
    int i0 = b * 1024 + t * 4;
    int s = 0;
    if (i0 + 3 < N) {
        int4 v = *(const int4*)(deg + i0);
        s = v.x + v.y + v.z + v.w;
    } else {
        for (int k = 0; k < 4; ++k) { int i = i0 + k; if (i < N) s += deg[i]; }
    }
    #pragma unroll
    for (int off = 32; off; off >>= 1) s += __shfl_down(s, off, 64);
    if (lane == 0) wsum[wid] = s;
    __syncthreads();
    if (t == 0) bsum[b] = wsum[0] + wsum[1] + wsum[2] + wsum[3];
}

__global__ __launch_bounds__(64) void scanB_kernel(int* __restrict__ bsum, int NB,
                                                   int* __restrict__ row_ptr, int N) {
    int t = threadIdx.x;
    int v = (t < NB) ? bsum[t] : 0;
    int x = v;
    #pragma unroll
    for (int off = 1; off < 64; off <<= 1) {
        int y = __shfl_up(x, off, 64);
        if (t >= off) x += y;
    }
    if (t < NB) bsum[t] = x - v;
    if (t == 63) row_ptr[N] = x;
}

__global__ __launch_bounds__(256) void scanC_kernel(const int* __restrict__ deg, const int* __restrict__ bsum,
                                                    int* __restrict__ row_ptr, int N) {
    __shared__ int wsum[4];
    int b = blockIdx.x, t = threadIdx.x, lane = t & 63, wid = t >> 6;
    int i0 = b * 1024 + t * 4;
    int4 v = make_int4(0, 0, 0, 0);
    if (i0 + 3 < N) v = *(const int4*)(deg + i0);
    else {
        v.x = (i0 < N) ? deg[i0] : 0;
        v.y = (i0 + 1 < N) ? deg[i0 + 1] : 0;
        v.z = (i0 + 2 < N) ? deg[i0 + 2] : 0;
        v.w = (i0 + 3 < N) ? deg[i0 + 3] : 0;
    }
    int tsum = v.x + v.y + v.z + v.w;
    int x = tsum;
    #pragma unroll
    for (int off = 1; off < 64; off <<= 1) {
        int y = __shfl_up(x, off, 64);
        if (lane >= off) x += y;
    }
    if (lane == 63) wsum[wid] = x;
    __syncthreads();
    int woff = 0;
    for (int k = 0; k < wid; ++k) woff += wsum[k];
    int base = bsum[b] + woff + (x - tsum);
    int e0 = base, e1 = e0 + v.x, e2 = e1 + v.y, e3 = e2 + v.z;
    if (i0 + 3 < N) *(int4*)(row_ptr + i0) = make_int4(e0, e1, e2, e3);
    else {
        if (i0 < N) row_ptr[i0] = e0;
        if (i0 + 1 < N) row_ptr[i0 + 1] = e1;
        if (i0 + 2 < N) row_ptr[i0 + 2] = e2;
        if (i0 + 3 < N) row_ptr[i0 + 3] = e3;
    }
}

__global__ __launch_bounds__(256) void offsets_kernel(unsigned int* __restrict__ part,
                                                      const int* __restrict__ row_ptr, int N) {
    int d = blockIdx.x * 256 + threadIdx.x;
    if (d >= N) return;
    int c = d >> CHUNK_SHIFT, idx = d & (CHUNK - 1);
    unsigned int* p = part + (((size_t)c * NSLICES) << CHUNK_SHIFT) + idx;
    unsigned int running = (unsigned int)row_ptr[d];
    #pragma unroll
    for (int s = 0; s < NSLICES; ++s) {
        unsigned int v = __builtin_nontemporal_load(p + ((size_t)s << CHUNK_SHIFT));
        __builtin_nontemporal_store(running, p + ((size_t)s << CHUNK_SHIFT));
        running += v & 0xFFFFu;
    }
}

__global__ __launch_bounds__(256) void scatter_kernel(const int* __restrict__ src, const int* __restrict__ dst,
                                                      const unsigned int* __restrict__ cum,
                                                      int* __restrict__ col, int E, int per) {
    __shared__ int cur[CHUNK];
    int c = blockIdx.y, s = blockIdx.x, t = threadIdx.x;
    const unsigned int* cc = cum + (((size_t)(c * NSLICES + s)) << CHUNK_SHIFT);
    #pragma unroll
    for (int i = 0; i < CHUNK / 256; ++i) cur[i * 256 + t] = (int)__builtin_nontemporal_load(cc + i * 256 + t);
    __syncthreads();
    int base = c << CHUNK_SHIFT;
    int beg = s * per;
    int end = min(E, beg + per);
    int nv = (end - beg) >> 2;
    const iv4* d4 = (const iv4*)(dst + beg);
    const iv4* s4 = (const iv4*)(src + beg);
    for (int i = t; i < nv; i += 256) {
        iv4 dv = __builtin_nontemporal_load(d4 + i);
        iv4 sv = __builtin_nontemporal_load(s4 + i);
        int x;
        x = dv.x - base; if ((unsigned)x < CHUNK) col[atomicAdd(&cur[x], 1)] = sv.x;
        x = dv.y - base; if ((unsigned)x < CHUNK) col[atomicAdd(&cur[x], 1)] = sv.y;
        x = dv.z - base; if ((unsigned)x < CHUNK) col[atomicAdd(&cur[x], 1)] = sv.z;
        x = dv.w - base; if ((unsigned)x < CHUNK) col[atomicAdd(&cur[x], 1)] = sv.w;
    }
    for (int e = beg + (nv << 2) + t; e < end; e += 256) {
        int x = dst[e] - base;
        if ((unsigned)x < CHUNK) col[atomicAdd(&cur[x], 1)] = src[e];
    }
}

// ---------------- dense layers ----------------

// h1[n][jb+j] = bf16( norm[n] * sum_k x[n][k] * W[k][jb+j] ), flat [n][128]
__global__ __launch_bounds__(256) void gemm1_kernel(const float* __restrict__ x, const float* __restrict__ norm,
                                                    const float* __restrict__ W, unsigned short* __restrict__ h1u,
                                                    int N) {
    __shared__ float xs[128 * 32];
    __shared__ float ws[128 * 64];
    int t = threadIdx.x;
    int rb = blockIdx.x * 32;
    int jb = blockIdx.y * 64;
    #pragma unroll
    for (int i = 0; i < 8; ++i) {
        int idx = i * 256 + t;
        int k = idx >> 4, j4 = (idx & 15) << 2;
        *(float4*)(ws + k * 64 + j4) = *(const float4*)(W + k * 128 + jb + j4);
    }
    #pragma unroll
    for (int i = 0; i < 4; ++i) {
        int idx = i * 256 + t;
        int row = idx >> 5, m = idx & 31, k4 = m << 2;
        int gr = rb + row;
        float4 v = make_float4(0.f, 0.f, 0.f, 0.f);
        if (gr < N) {
            v = *(const float4*)(x + (size_t)gr * 128 + k4);
            float nm = norm[gr];
            v.x *= nm; v.y *= nm; v.z *= nm; v.w *= nm;
        }
        int r = row ^ ((m & 7) << 2);
        xs[(k4 + 0) * 32 + r] = v.x;
        xs[(k4 + 1) * 32 + r] = v.y;
        xs[(k4 + 2) * 32 + r] = v.z;
        xs[(k4 + 3) * 32 + r] = v.w;
    }
    __syncthreads();
    int jg = t & 15, rg = t >> 4;
    int j = jg << 2, r0 = rg << 1;
    float a00 = 0, a01 = 0, a02 = 0, a03 = 0;
    float a10 = 0, a11 = 0, a12 = 0, a13 = 0;
    #pragma unroll 8
    for (int k = 0; k < 128; ++k) {
        int sw = ((k >> 2) & 7) << 2;
        float2 xv = *(const float2*)&xs[k * 32 + (r0 ^ sw)];
        float4 wv = *(const float4*)&ws[k * 64 + j];
        a00 += xv.x * wv.x; a01 += xv.x * wv.y; a02 += xv.x * wv.z; a03 += xv.x * wv.w;
        a10 += xv.y * wv.x; a11 += xv.y * wv.y; a12 += xv.y * wv.z; a13 += xv.y * wv.w;
    }
    int gr0 = rb + r0;
    if (gr0 < N) {
        uint2 p = make_uint2(pack_bf2(a00, a01), pack_bf2(a02, a03));
        *(uint2*)(h1u + (size_t)gr0 * 128 + jb + j) = p;
    }
    if (gr0 + 1 < N) {
        uint2 p = make_uint2(pack_bf2(a10, a11), pack_bf2(a12, a13));
        *(uint2*)(h1u + (size_t)(gr0 + 1) * 128 + jb + j) = p;
    }
}

// agg1: wave = 4 nodes x 16 lanes; lane loads uint4 = 8 bf16 feats.
// Branch-free per-group edge loop (groups diverge via exec mask only).
__global__ __launch_bounds__(256) void agg1_kernel(const int* __restrict__ row_ptr, const int* __restrict__ col,
                                                   const uint4* __restrict__ h1q, const float* __restrict__ norm_dst,
                                                   const float* __restrict__ b1, uint4* __restrict__ x2q, int N) {
    int t = threadIdx.x;
    int wid = t >> 6, lane = t & 63;
    int g = lane >> 4, f = lane & 15;
    int nb = (blockIdx.x * 4 + wid) * 4 + g;
    bool valid = nb < N;
    int beg = 0, deg = 0;
    if (valid) { beg = row_ptr[nb]; deg = row_ptr[nb + 1] - beg; }
    const int* cp = col + beg;
    float a0 = 0, a1 = 0, a2 = 0, a3 = 0, a4 = 0, a5 = 0, a6 = 0, a7 = 0;
    int e = 0;
    for (; e + 4 <= deg; e += 4) {
        int s0 = cp[e], s1 = cp[e + 1], s2 = cp[e + 2], s3 = cp[e + 3];
        uint4 v0 = h1q[(size_t)s0 * 16 + f];
        uint4 v1 = h1q[(size_t)s1 * 16 + f];
        uint4 v2 = h1q[(size_t)s2 * 16 + f];
        uint4 v3 = h1q[(size_t)s3 * 16 + f];
        a0 += bflo(v0.x); a1 += bfhi(v0.x); a2 += bflo(v0.y); a3 += bfhi(v0.y);
        a4 += bflo(v0.z); a5 += bfhi(v0.z); a6 += bflo(v0.w); a7 += bfhi(v0.w);
        a0 += bflo(v1.x); a1 += bfhi(v1.x); a2 += bflo(v1.y); a3 += bfhi(v1.y);
        a4 += bflo(v1.z); a5 += bfhi(v1.z); a6 += bflo(v1.w); a7 += bfhi(v1.w);
        a0 += bflo(v2.x); a1 += bfhi(v2.x); a2 += bflo(v2.y); a3 += bfhi(v2.y);
        a4 += bflo(v2.z); a5 += bfhi(v2.z); a6 += bflo(v2.w); a7 += bfhi(v2.w);
        a0 += bflo(v3.x); a1 += bfhi(v3.x); a2 += bflo(v3.y); a3 += bfhi(v3.y);
        a4 += bflo(v3.z); a5 += bfhi(v3.z); a6 += bflo(v3.w); a7 += bfhi(v3.w);
    }
    for (; e < deg; ++e) {
        int s = cp[e];
        uint4 v = h1q[(size_t)s * 16 + f];
        a0 += bflo(v.x); a1 += bfhi(v.x); a2 += bflo(v.y); a3 += bfhi(v.y);
        a4 += bflo(v.z); a5 += bfhi(v.z); a6 += bflo(v.w); a7 += bfhi(v.w);
    }
    if (valid) {
        float nd = norm_dst[nb];
        float4 bA = *(const float4*)(b1 + f * 8);
        float4 bB = *(const float4*)(b1 + f * 8 + 4);
        float o0 = fmaxf(a0 * nd + bA.x, 0.f);
        float o1 = fmaxf(a1 * nd + bA.y, 0.f);
        float o2 = fmaxf(a2 * nd + bA.z, 0.f);
        float o3 = fmaxf(a3 * nd + bA.w, 0.f);
        float o4 = fmaxf(a4 * nd + bB.x, 0.f);
        float o5 = fmaxf(a5 * nd + bB.y, 0.f);
        float o6 = fmaxf(a6 * nd + bB.z, 0.f);
        float o7 = fmaxf(a7 * nd + bB.w, 0.f);
        uint4 p;
        p.x = pack_bf2(o0, o1); p.y = pack_bf2(o2, o3);
        p.z = pack_bf2(o4, o5); p.w = pack_bf2(o6, o7);
        x2q[(size_t)nb * 16 + f] = p;
    }
}

// h2[n][j] = bf16( norm[n] * sum_k x2[n][k] * W2[k][j] )   (W2 is 128x40)
__global__ __launch_bounds__(256) void gemm2_kernel(const unsigned int* __restrict__ x2p, const float* __restrict__ norm,
                                                    const float* __restrict__ W, unsigned short* __restrict__ h2u, int N) {
    __shared__ float xs[128 * 64];
    __shared__ float ws2[128 * 40];
    int t = threadIdx.x;
    int rb = blockIdx.x * 64;
    #pragma unroll
    for (int i = 0; i < 5; ++i) {
        int idx = i * 256 + t;
        *(float4*)(ws2 + idx * 4) = *(const float4*)(W + idx * 4);
    }
    #pragma unroll
    for (int i = 0; i < 16; ++i) {
        int idx = i * 256 + t;               // 64 rows x 64 k-pairs
        int row = idx >> 6, kp = idx & 63;
        int gr = rb + row;
        unsigned v = 0; float nm = 0.f;
        if (gr < N) {
            v = x2p[(size_t)gr * 64 + kp];
            nm = norm[gr];
        }
        int r = row ^ (((kp >> 1) & 7) << 2);
        xs[(2 * kp + 0) * 64 + r] = bflo(v) * nm;
        xs[(2 * kp + 1) * 64 + r] = bfhi(v) * nm;
    }
    __syncthreads();
    int jg = t & 7, rg = t >> 3;
    int j = jg * 5, r0 = rg << 1;
    float acc0[5] = {0, 0, 0, 0, 0};
    float acc1[5] = {0, 0, 0, 0, 0};
    #pragma unroll 4
    for (int k = 0; k < 128; ++k) {
        int sw = ((k >> 2) & 7) << 2;
        float2 xv = *(const float2*)&xs[k * 64 + (r0 ^ sw)];
        #pragma unroll
        for (int c = 0; c < 5; ++c) {
            float w = ws2[k * 40 + j + c];
            acc0[c] += xv.x * w;
            acc1[c] += xv.y * w;
        }
    }
    int gr0 = rb + r0;
    if (gr0 < N) {
        #pragma unroll
        for (int c = 0; c < 5; ++c) h2u[(size_t)gr0 * 40 + j + c] = (unsigned short)f2bf_bits(acc0[c]);
    }
    if (gr0 + 1 < N) {
        #pragma unroll
        for (int c = 0; c < 5; ++c) h2u[(size_t)(gr0 + 1) * 40 + j + c] = (unsigned short)f2bf_bits(acc1[c]);
    }
}

// One wave per node (40 active lanes): out = sum h2[src] * norm_dst + b2
__global__ __launch_bounds__(256) void agg2_kernel(const int* __restrict__ row_ptr, const int* __restrict__ col,
                                                   const unsigned short* __restrict__ h2u, const float* __restrict__ norm_dst,
                                                   const float* __restrict__ b2, float* __restrict__ out, int N) {
    int n = (blockIdx.x * 256 + threadIdx.x) >> 6;
    int lane = threadIdx.x & 63;
    if (n >= N) return;
    int beg = row_ptr[n], end = row_ptr[n + 1];
    float acc = 0.f;
    bool act = lane < 40;
    int e = beg;
    for (; e + 4 <= end; e += 4) {
        int s0 = col[e], s1 = col[e + 1], s2 = col[e + 2], s3 = col[e + 3];
        if (act) {
            acc += __uint_as_float((unsigned)h2u[(size_t)s0 * 40 + lane] << 16);
            acc += __uint_as_float((unsigned)h2u[(size_t)s1 * 40 + lane] << 16);
            acc += __uint_as_float((unsigned)h2u[(size_t)s2 * 40 + lane] << 16);
            acc += __uint_as_float((unsigned)h2u[(size_t)s3 * 40 + lane] << 16);
        }
    }
    for (; e < end; ++e) {
        int s = col[e];
        if (act) acc += __uint_as_float((unsigned)h2u[(size_t)s * 40 + lane] << 16);
    }
    if (act) out[(size_t)n * 40 + lane] = acc * norm_dst[n] + b2[lane];
}

extern "C" void kernel_launch(void* const* d_in, const int* in_sizes, int n_in,
                              void* d_out, int out_size, void* d_ws, size_t ws_size,
                              hipStream_t stream) {
    const float* x  = (const float*)d_in[0];
    const int* src  = (const int*)d_in[1];
    const int* dst  = (const int*)d_in[2];
    const float* W1 = (const float*)d_in[3];
    const float* b1 = (const float*)d_in[4];
    const float* W2 = (const float*)d_in[5];
    const float* b2 = (const float*)d_in[6];
    float* out = (float*)d_out;

    int N = in_sizes[0] / 128;
    int E = in_sizes[1];
    int NPAD = (N + 63) & ~63;
    int NCHUNKS = (N + CHUNK - 1) >> CHUNK_SHIFT;
    int per = ((E + NSLICES - 1) / NSLICES + 3) & ~3;
    int NB = (N + 1023) / 1024;

    float* ws = (float*)d_ws;
    float* norm_src = ws;                                  // NPAD floats
    float* norm_dst = ws + NPAD;                           // NPAD floats
    int* deg_dst_i  = (int*)(ws + 2 * (size_t)NPAD);       // NPAD ints
    int* row_ptr    = (int*)(ws + 3 * (size_t)NPAD);       // N+1 ints
    int* bsum       = (int*)(ws + 4 * (size_t)NPAD);       // NB (<=64) ints
    int* col        = (int*)(ws + 4 * (size_t)NPAD + 64);  // E ints
    size_t h1_off   = ((size_t)4 * NPAD + 64 + E + 15) & ~(size_t)15;
    unsigned short* h1u = (unsigned short*)(ws + h1_off);  // NPAD*128 bf16 (12.8MB)
    uint4* h1q      = (uint4*)h1u;
    uint4* x2q      = h1q + (size_t)NPAD * 16;             // h1 is NPAD*16 uint4s (256B/row)
    unsigned int* x2p = (unsigned int*)x2q;
    unsigned short* h2u = h1u;                             // reuse (h1 dead after agg1)
    unsigned int* part = (unsigned int*)h1u;               // 16MB, dead before gemm1

    dim3 cgrid(NSLICES, NCHUNKS);
    count_kernel<<<cgrid, 256, 0, stream>>>(src, dst, part, E, per);
    reduce_kernel<<<(N + 255) / 256, 256, 0, stream>>>(part, norm_src, norm_dst, deg_dst_i, N);
    scanA_kernel<<<NB, 256, 0, stream>>>(deg_dst_i, bsum, N);
    scanB_kernel<<<1, 64, 0, stream>>>(bsum, NB, row_ptr, N);
    scanC_kernel<<<NB, 256, 0, stream>>>(deg_dst_i, bsum, row_ptr, N);
    offsets_kernel<<<(N + 255) / 256, 256, 0, stream>>>(part, row_ptr, N);
    scatter_kernel<<<cgrid, 256, 0, stream>>>(src, dst, part, col, E, per);
    gemm1_kernel<<<dim3((N + 31) / 32, 2), 256, 0, stream>>>(x, norm_src, W1, h1u, N);
    agg1_kernel<<<(N + 15) / 16, 256, 0, stream>>>(row_ptr, col, h1q, norm_dst, b1, x2q, N);
    gemm2_kernel<<<(N + 63) / 64, 256, 0, stream>>>(x2p, norm_src, W2, h2u, N);
    agg2_kernel<<<(N * 64 + 255) / 256, 256, 0, stream>>>(row_ptr, col, h2u, norm_dst, b2, out, N);
}